// Round 5
// baseline (553.994 us; speedup 1.0000x reference)
//
#include <hip/hip_runtime.h>
#include <stdint.h>

#define BATCH   8
#define LEN0    8192
#define EMB     768
#define NDEPTH  4
#define POOLED  512   // LEN0 >> NDEPTH

// ---------------------------------------------------------------------------
// ws layout (bytes):
//   scA   : BATCH*LEN0 f32   @ 0x000000
//   scB   : BATCH*LEN0 f32   @ 0x040000
//   rank  : BATCH*LEN0 u32   @ 0x080000
//   ior   : BATCH*LEN0 u32   @ 0x0C0000  (idx_of_rank)
//   liA   : BATCH*LEN0 u32   @ 0x100000  (leaf-index lists)
//   lwA   : BATCH*LEN0 f32   @ 0x140000  (leaf-weight lists)
//   liB   : BATCH*LEN0 u32   @ 0x180000
//   lwB   : BATCH*LEN0 f32   @ 0x1C0000
// total 2 MiB
// ---------------------------------------------------------------------------

// Bit-faithful replication of numpy's SIMD float32 exp
// (numpy loops_exponent_log.dispatch.c.src, AVX512F/AVX2 path):
//   quadrant = RNE(x * LOG2EF)          (f32 multiply, magic-number round)
//   r = fnmadd(q, C1, x); r = fnmadd(q, C2, x)   C1=0.693359375, C2=-2.12194440e-4
//   poly = Horner(p0..p5); poly = fma(poly, r*r, r); poly += 1
//   result = poly * 2^q                 (exponent-bit construction)
// Domain here is [-~30, 0]: no overflow/underflow/denormal handling needed.
__device__ __forceinline__ float npy_expf(float x) {
    const float q = rintf(__fmul_rn(x, 1.44269504088896341f)); // LOG2EF
    float r = __fmaf_rn(q, -0.693359375f, x);       // fnmadd(q, C1, x)
    r = __fmaf_rn(q, 2.12194440e-4f, r);            // fnmadd(q, C2, x), C2 negative
    const float r2 = __fmul_rn(r, r);
    float p = 1.9875691500E-4f;
    p = __fmaf_rn(p, r, 1.3981999507E-3f);
    p = __fmaf_rn(p, r, 8.3334519073E-3f);
    p = __fmaf_rn(p, r, 4.1665795894E-2f);
    p = __fmaf_rn(p, r, 1.6666665459E-1f);
    p = __fmaf_rn(p, r, 5.0000001201E-1f);
    p = __fmaf_rn(p, r2, r);
    p = __fadd_rn(p, 1.0f);
    const int qi = (int)q;
    const float sc = __uint_as_float((uint32_t)((qi + 127) << 23));
    return __fmul_rn(p, sc);
}

__global__ void k_init(const float* __restrict__ scores_in,
                       float* __restrict__ sc0,
                       uint32_t* __restrict__ li0,
                       float* __restrict__ lw0) {
    int i = blockIdx.x * 256 + threadIdx.x;   // over BATCH*LEN0
    sc0[i] = scores_in[i];                    // [B,8192,1] flat == b*8192+i
    li0[i] = (uint32_t)(i & (LEN0 - 1));
    lw0[i] = 1.0f;
}

// rank-by-count on f32 scores, stable (ascending-index) tie order:
// rank(i) = #{ j : s_j > s_i  or  (s_j == s_i and j < i) } == stable argsort(-s)
__global__ __launch_bounds__(256) void k_rank(const float* __restrict__ sc,
                                              uint32_t* __restrict__ rank,
                                              uint32_t* __restrict__ ior,
                                              int L) {
    __shared__ float keys[LEN0];  // 32 KiB
    const int b = blockIdx.y;
    const int base = b * LEN0;
    const int tid = threadIdx.x;

    for (int j = tid; j < L; j += 256)
        keys[j] = sc[base + j];
    __syncthreads();

    const int i = blockIdx.x * 256 + tid;
    const float me = keys[i];

    uint32_t c0 = 0, c1 = 0, c2 = 0, c3 = 0;
    #pragma unroll 4
    for (int j = 0; j < L; j += 4) {
        c0 += (keys[j]     > me) || (keys[j]     == me && (j    ) < i);
        c1 += (keys[j + 1] > me) || (keys[j + 1] == me && (j + 1) < i);
        c2 += (keys[j + 2] > me) || (keys[j + 2] == me && (j + 2) < i);
        c3 += (keys[j + 3] > me) || (keys[j + 3] == me && (j + 3) < i);
    }
    const uint32_t r = c0 + c1 + c2 + c3;
    rank[base + i] = r;
    ior[base + r] = (uint32_t)i;   // inverse permutation (ranks unique)
}

// per-batch: prefix-scan of top flags (SORT_BACK destination), f32 pair
// softmax matching the numpy reference op order, and leaf-list merge.
__global__ __launch_bounds__(1024) void k_pair(const float* __restrict__ sc_cur,
                                               float* __restrict__ sc_nxt,
                                               const uint32_t* __restrict__ rank,
                                               const uint32_t* __restrict__ ior,
                                               const uint32_t* __restrict__ li_cur,
                                               const float* __restrict__ lw_cur,
                                               uint32_t* __restrict__ li_nxt,
                                               float* __restrict__ lw_nxt,
                                               int L, int W) {
    __shared__ uint32_t part[1024];
    const int b = blockIdx.x;
    const int tid = threadIdx.x;
    const int base = b * LEN0;
    const int R = L / 1024;              // 8,4,2,1
    const int i0 = tid * R;
    const uint32_t half = (uint32_t)(L / 2);

    uint32_t flags[8];
    uint32_t loc = 0;
    for (int k = 0; k < R; k++) {
        uint32_t f = (rank[base + i0 + k] < half) ? 1u : 0u;
        flags[k] = f;
        loc += f;
    }
    part[tid] = loc;
    __syncthreads();
    // Hillis-Steele inclusive scan over 1024 partials
    for (int off = 1; off < 1024; off <<= 1) {
        uint32_t v = part[tid];
        uint32_t add = (tid >= off) ? part[tid - off] : 0u;
        __syncthreads();
        part[tid] = v + add;
        __syncthreads();
    }
    uint32_t dst = (tid > 0) ? part[tid - 1] : 0u;   // exclusive prefix

    for (int k = 0; k < R; k++) {
        if (!flags[k]) continue;
        const int i = i0 + k;
        const uint32_t r = rank[base + i];
        const uint32_t p = ior[base + (uint32_t)(L - 1) - r];

        const float s0 = sc_cur[base + i];
        const float s1 = sc_cur[base + p];
        // np.power(2.0, s): scalar glibc powf (correctly rounded in practice);
        // exp2 in double rounded to f32 reproduces it.
        const float p0 = (float)exp2((double)s0);
        const float p1 = (float)exp2((double)s1);
        // softmax over the pair: max-subtract, numpy expf, sum, divide
        const float mx = fmaxf(p0, p1);
        const float d0 = __fsub_rn(p0, mx);
        const float d1 = __fsub_rn(p1, mx);
        const float e0 = npy_expf(d0);
        const float e1 = npy_expf(d1);
        const float den = __fadd_rn(e0, e1);
        const float w0 = __fdiv_rn(e0, den);
        const float w1 = __fdiv_rn(e1, den);
        const float ns = __fadd_rn(__fmul_rn(s0, w0), __fmul_rn(s1, w1));

        sc_nxt[base + dst] = ns;

        const uint32_t* liA = li_cur + base + i * W;
        const float*    lwA = lw_cur + base + i * W;
        const uint32_t* liB = li_cur + base + p * W;
        const float*    lwB = lw_cur + base + p * W;
        uint32_t* lo = li_nxt + base + dst * 2 * W;
        float*    wo = lw_nxt + base + dst * 2 * W;
        for (int k2 = 0; k2 < W; k2++) { lo[k2]     = liA[k2]; wo[k2]     = __fmul_rn(w0, lwA[k2]); }
        for (int k2 = 0; k2 < W; k2++) { lo[W + k2] = liB[k2]; wo[W + k2] = __fmul_rn(w1, lwB[k2]); }
        dst++;
    }
}

// final gather: out[b,s,:] = sum_{k<16} w_k * emb[b, idx_k, :]
__global__ __launch_bounds__(192) void k_merge(const float* __restrict__ emb,
                                               const uint32_t* __restrict__ li,
                                               const float* __restrict__ lw,
                                               const float* __restrict__ sc_fin,
                                               float* __restrict__ out) {
    __shared__ uint32_t idx[16];
    __shared__ float    w[16];
    const int s = blockIdx.x;
    const int b = blockIdx.y;
    const int d = threadIdx.x;

    if (d < 16) {
        idx[d] = li[b * LEN0 + s * 16 + d];
        w[d]   = lw[b * LEN0 + s * 16 + d];
    }
    __syncthreads();

    const float* ebase = emb + (size_t)b * LEN0 * EMB;
    float4 acc = make_float4(0.f, 0.f, 0.f, 0.f);
    #pragma unroll
    for (int k = 0; k < 16; k++) {
        const float4 v = *(const float4*)(ebase + (size_t)idx[k] * EMB + d * 4);
        const float wk = w[k];
        acc.x += wk * v.x; acc.y += wk * v.y; acc.z += wk * v.z; acc.w += wk * v.w;
    }
    *(float4*)(out + ((size_t)b * POOLED + s) * EMB + d * 4) = acc;
    if (d == 0)
        out[(size_t)BATCH * POOLED * EMB + b * POOLED + s] = sc_fin[b * LEN0 + s];
}

extern "C" void kernel_launch(void* const* d_in, const int* in_sizes, int n_in,
                              void* d_out, int out_size, void* d_ws, size_t ws_size,
                              hipStream_t stream) {
    const float* embs   = (const float*)d_in[0];
    const float* scores = (const float*)d_in[1];
    float* out = (float*)d_out;
    char* ws = (char*)d_ws;

    float*    scA  = (float*)(ws + 0x000000);
    float*    scB  = (float*)(ws + 0x040000);
    uint32_t* rank = (uint32_t*)(ws + 0x080000);
    uint32_t* ior  = (uint32_t*)(ws + 0x0C0000);
    uint32_t* liA  = (uint32_t*)(ws + 0x100000);
    float*    lwA  = (float*)(ws + 0x140000);
    uint32_t* liB  = (uint32_t*)(ws + 0x180000);
    float*    lwB  = (float*)(ws + 0x1C0000);

    k_init<<<(BATCH * LEN0) / 256, 256, 0, stream>>>(scores, scA, liA, lwA);

    float *sc_cur = scA, *sc_nxt = scB;
    uint32_t *li_cur = liA, *li_nxt = liB;
    float *lw_cur = lwA, *lw_nxt = lwB;

    int L = LEN0;
    for (int l = 0; l < NDEPTH; l++) {
        const int W = 1 << l;
        k_rank<<<dim3(L / 256, BATCH), 256, 0, stream>>>(sc_cur, rank, ior, L);
        k_pair<<<BATCH, 1024, 0, stream>>>(sc_cur, sc_nxt, rank, ior,
                                           li_cur, lw_cur, li_nxt, lw_nxt, L, W);
        { float* t = sc_cur; sc_cur = sc_nxt; sc_nxt = t; }
        { uint32_t* t = li_cur; li_cur = li_nxt; li_nxt = t; }
        { float* t = lw_cur; lw_cur = lw_nxt; lw_nxt = t; }
        L >>= 1;
    }

    k_merge<<<dim3(POOLED, BATCH), 192, 0, stream>>>(embs, li_cur, lw_cur, sc_cur, out);
}

// Round 6
// 260.593 us; speedup vs baseline: 2.1259x; 2.1259x over previous
//
#include <hip/hip_runtime.h>
#include <stdint.h>

#define BATCH   8
#define LEN0    8192
#define EMB     768
#define NDEPTH  4
#define POOLED  512   // LEN0 >> NDEPTH
#define NJ      4     // j-chunks per level in k_rank

// ---------------------------------------------------------------------------
// ws layout (bytes):
//   scA   : BATCH*LEN0 f32   @ 0x000000
//   scB   : BATCH*LEN0 f32   @ 0x040000
//   rank  : BATCH*LEN0 u32   @ 0x080000
//   ior   : BATCH*LEN0 u32   @ 0x0C0000  (idx_of_rank)
//   liA   : BATCH*LEN0 u32   @ 0x100000  (leaf-index lists)
//   lwA   : BATCH*LEN0 f32   @ 0x140000  (leaf-weight lists)
//   liB   : BATCH*LEN0 u32   @ 0x180000
//   lwB   : BATCH*LEN0 f32   @ 0x1C0000
//   rankp : NJ*BATCH*LEN0 u32 @ 0x200000 (partial counts, 1 MiB)
// total 3 MiB
// ---------------------------------------------------------------------------

// Bit-faithful replication of numpy's SIMD float32 exp — DO NOT TOUCH.
// (Round 5 proved this is the exact variable that makes ranks match the
// numpy golden: Horner + fnmadd reduction + exponent-bit scale.)
__device__ __forceinline__ float npy_expf(float x) {
    const float q = rintf(__fmul_rn(x, 1.44269504088896341f)); // LOG2EF
    float r = __fmaf_rn(q, -0.693359375f, x);       // fnmadd(q, C1, x)
    r = __fmaf_rn(q, 2.12194440e-4f, r);            // fnmadd(q, C2, x), C2 negative
    const float r2 = __fmul_rn(r, r);
    float p = 1.9875691500E-4f;
    p = __fmaf_rn(p, r, 1.3981999507E-3f);
    p = __fmaf_rn(p, r, 8.3334519073E-3f);
    p = __fmaf_rn(p, r, 4.1665795894E-2f);
    p = __fmaf_rn(p, r, 1.6666665459E-1f);
    p = __fmaf_rn(p, r, 5.0000001201E-1f);
    p = __fmaf_rn(p, r2, r);
    p = __fadd_rn(p, 1.0f);
    const int qi = (int)q;
    const float sc = __uint_as_float((uint32_t)((qi + 127) << 23));
    return __fmul_rn(p, sc);
}

__global__ void k_init(const float* __restrict__ scores_in,
                       float* __restrict__ sc0,
                       uint32_t* __restrict__ li0,
                       float* __restrict__ lw0) {
    int i = blockIdx.x * 256 + threadIdx.x;   // over BATCH*LEN0
    sc0[i] = scores_in[i];                    // [B,8192,1] flat == b*8192+i
    li0[i] = (uint32_t)(i & (LEN0 - 1));
    lw0[i] = 1.0f;
}

// Chunked rank-by-count, stable (ascending-index) tie order.
// Block (bx, cy, bz): i-range [bx*256, bx*256+256), j-chunk [cy*C, cy*C+C)
// of batch bz. Writes partial count to rankp[cy]. Rank values produced after
// summation are bit-identical to the monolithic version (integer sums).
__global__ __launch_bounds__(256) void k_rank(const float* __restrict__ sc,
                                              uint32_t* __restrict__ rankp,
                                              int L, int C) {
    __shared__ float keys[2048];             // C <= 2048 -> 8 KiB
    const int b    = blockIdx.z;
    const int base = b * LEN0;
    const int tid  = threadIdx.x;
    const int ib   = blockIdx.x * 256;
    const int jb   = blockIdx.y * C;

    for (int j = tid; j < C; j += 256)
        keys[j] = sc[base + jb + j];
    __syncthreads();

    const int i = ib + tid;
    const float me = sc[base + i];

    uint32_t cnt = 0;
    if (jb + C <= ib) {
        // whole chunk has j < i: tie contributes -> count (k >= me)
        for (int j = 0; j < C; j += 4) {
            const float4 kv = *(const float4*)&keys[j];
            cnt += (kv.x >= me);
            cnt += (kv.y >= me);
            cnt += (kv.z >= me);
            cnt += (kv.w >= me);
        }
    } else if (jb >= ib + 256) {
        // whole chunk has j > i: tie never contributes -> count (k > me)
        for (int j = 0; j < C; j += 4) {
            const float4 kv = *(const float4*)&keys[j];
            cnt += (kv.x > me);
            cnt += (kv.y > me);
            cnt += (kv.z > me);
            cnt += (kv.w > me);
        }
    } else {
        // diagonal chunk: full stable predicate
        for (int j = 0; j < C; j += 4) {
            const float4 kv = *(const float4*)&keys[j];
            const int jj = jb + j;
            cnt += (kv.x > me) || (kv.x == me && (jj    ) < i);
            cnt += (kv.y > me) || (kv.y == me && (jj + 1) < i);
            cnt += (kv.z > me) || (kv.z == me && (jj + 2) < i);
            cnt += (kv.w > me) || (kv.w == me && (jj + 3) < i);
        }
    }
    rankp[(size_t)blockIdx.y * (BATCH * LEN0) + base + i] = cnt;
}

// sum NJ partial counts -> rank; build inverse permutation ior
__global__ __launch_bounds__(256) void k_scatter(const uint32_t* __restrict__ rankp,
                                                 uint32_t* __restrict__ rank,
                                                 uint32_t* __restrict__ ior) {
    const int b    = blockIdx.y;
    const int base = b * LEN0;
    const int i    = blockIdx.x * 256 + threadIdx.x;
    uint32_t r = 0;
    #pragma unroll
    for (int c = 0; c < NJ; c++)
        r += rankp[(size_t)c * (BATCH * LEN0) + base + i];
    rank[base + i] = r;
    ior[base + r] = (uint32_t)i;
}

// per-batch: prefix-scan of top flags (SORT_BACK destination), f32 pair
// softmax matching the numpy reference op order, and leaf-list merge.
// NUMERICS FROZEN (verified round 5).
__global__ __launch_bounds__(1024) void k_pair(const float* __restrict__ sc_cur,
                                               float* __restrict__ sc_nxt,
                                               const uint32_t* __restrict__ rank,
                                               const uint32_t* __restrict__ ior,
                                               const uint32_t* __restrict__ li_cur,
                                               const float* __restrict__ lw_cur,
                                               uint32_t* __restrict__ li_nxt,
                                               float* __restrict__ lw_nxt,
                                               int L, int W) {
    __shared__ uint32_t part[1024];
    const int b = blockIdx.x;
    const int tid = threadIdx.x;
    const int base = b * LEN0;
    const int R = L / 1024;              // 8,4,2,1
    const int i0 = tid * R;
    const uint32_t half = (uint32_t)(L / 2);

    uint32_t flags[8];
    uint32_t loc = 0;
    for (int k = 0; k < R; k++) {
        uint32_t f = (rank[base + i0 + k] < half) ? 1u : 0u;
        flags[k] = f;
        loc += f;
    }
    part[tid] = loc;
    __syncthreads();
    // Hillis-Steele inclusive scan over 1024 partials
    for (int off = 1; off < 1024; off <<= 1) {
        uint32_t v = part[tid];
        uint32_t add = (tid >= off) ? part[tid - off] : 0u;
        __syncthreads();
        part[tid] = v + add;
        __syncthreads();
    }
    uint32_t dst = (tid > 0) ? part[tid - 1] : 0u;   // exclusive prefix

    for (int k = 0; k < R; k++) {
        if (!flags[k]) continue;
        const int i = i0 + k;
        const uint32_t r = rank[base + i];
        const uint32_t p = ior[base + (uint32_t)(L - 1) - r];

        const float s0 = sc_cur[base + i];
        const float s1 = sc_cur[base + p];
        // np.power(2.0, s): glibc powf (correctly rounded); exp2 in double
        // rounded to f32 reproduces it.
        const float p0 = (float)exp2((double)s0);
        const float p1 = (float)exp2((double)s1);
        // softmax over the pair: max-subtract, numpy expf, sum, divide
        const float mx = fmaxf(p0, p1);
        const float d0 = __fsub_rn(p0, mx);
        const float d1 = __fsub_rn(p1, mx);
        const float e0 = npy_expf(d0);
        const float e1 = npy_expf(d1);
        const float den = __fadd_rn(e0, e1);
        const float w0 = __fdiv_rn(e0, den);
        const float w1 = __fdiv_rn(e1, den);
        const float ns = __fadd_rn(__fmul_rn(s0, w0), __fmul_rn(s1, w1));

        sc_nxt[base + dst] = ns;

        const uint32_t* liA = li_cur + base + i * W;
        const float*    lwA = lw_cur + base + i * W;
        const uint32_t* liB = li_cur + base + p * W;
        const float*    lwB = lw_cur + base + p * W;
        uint32_t* lo = li_nxt + base + dst * 2 * W;
        float*    wo = lw_nxt + base + dst * 2 * W;
        for (int k2 = 0; k2 < W; k2++) { lo[k2]     = liA[k2]; wo[k2]     = __fmul_rn(w0, lwA[k2]); }
        for (int k2 = 0; k2 < W; k2++) { lo[W + k2] = liB[k2]; wo[W + k2] = __fmul_rn(w1, lwB[k2]); }
        dst++;
    }
}

// final gather: out[b,s,:] = sum_{k<16} w_k * emb[b, idx_k, :]
__global__ __launch_bounds__(192) void k_merge(const float* __restrict__ emb,
                                               const uint32_t* __restrict__ li,
                                               const float* __restrict__ lw,
                                               const float* __restrict__ sc_fin,
                                               float* __restrict__ out) {
    __shared__ uint32_t idx[16];
    __shared__ float    w[16];
    const int s = blockIdx.x;
    const int b = blockIdx.y;
    const int d = threadIdx.x;

    if (d < 16) {
        idx[d] = li[b * LEN0 + s * 16 + d];
        w[d]   = lw[b * LEN0 + s * 16 + d];
    }
    __syncthreads();

    const float* ebase = emb + (size_t)b * LEN0 * EMB;
    float4 acc = make_float4(0.f, 0.f, 0.f, 0.f);
    #pragma unroll
    for (int k = 0; k < 16; k++) {
        const float4 v = *(const float4*)(ebase + (size_t)idx[k] * EMB + d * 4);
        const float wk = w[k];
        acc.x += wk * v.x; acc.y += wk * v.y; acc.z += wk * v.z; acc.w += wk * v.w;
    }
    *(float4*)(out + ((size_t)b * POOLED + s) * EMB + d * 4) = acc;
    if (d == 0)
        out[(size_t)BATCH * POOLED * EMB + b * POOLED + s] = sc_fin[b * LEN0 + s];
}

extern "C" void kernel_launch(void* const* d_in, const int* in_sizes, int n_in,
                              void* d_out, int out_size, void* d_ws, size_t ws_size,
                              hipStream_t stream) {
    const float* embs   = (const float*)d_in[0];
    const float* scores = (const float*)d_in[1];
    float* out = (float*)d_out;
    char* ws = (char*)d_ws;

    float*    scA   = (float*)(ws + 0x000000);
    float*    scB   = (float*)(ws + 0x040000);
    uint32_t* rank  = (uint32_t*)(ws + 0x080000);
    uint32_t* ior   = (uint32_t*)(ws + 0x0C0000);
    uint32_t* liA   = (uint32_t*)(ws + 0x100000);
    float*    lwA   = (float*)(ws + 0x140000);
    uint32_t* liB   = (uint32_t*)(ws + 0x180000);
    float*    lwB   = (float*)(ws + 0x1C0000);
    uint32_t* rankp = (uint32_t*)(ws + 0x200000);

    k_init<<<(BATCH * LEN0) / 256, 256, 0, stream>>>(scores, scA, liA, lwA);

    float *sc_cur = scA, *sc_nxt = scB;
    uint32_t *li_cur = liA, *li_nxt = liB;
    float *lw_cur = lwA, *lw_nxt = lwB;

    int L = LEN0;
    for (int l = 0; l < NDEPTH; l++) {
        const int W = 1 << l;
        const int C = L / NJ;            // 2048,1024,512,256
        k_rank<<<dim3(L / 256, NJ, BATCH), 256, 0, stream>>>(sc_cur, rankp, L, C);
        k_scatter<<<dim3(L / 256, BATCH), 256, 0, stream>>>(rankp, rank, ior);
        k_pair<<<BATCH, 1024, 0, stream>>>(sc_cur, sc_nxt, rank, ior,
                                           li_cur, lw_cur, li_nxt, lw_nxt, L, W);
        { float* t = sc_cur; sc_cur = sc_nxt; sc_nxt = t; }
        { uint32_t* t = li_cur; li_cur = li_nxt; li_nxt = t; }
        { float* t = lw_cur; lw_cur = lw_nxt; lw_nxt = t; }
        L >>= 1;
    }

    k_merge<<<dim3(POOLED, BATCH), 192, 0, stream>>>(embs, li_cur, lw_cur, sc_cur, out);
}

// Round 7
// 244.549 us; speedup vs baseline: 2.2654x; 1.0656x over previous
//
#include <hip/hip_runtime.h>
#include <stdint.h>

#define BATCH   8
#define LEN0    8192
#define EMB     768
#define NDEPTH  4
#define POOLED  512   // LEN0 >> NDEPTH
#define NJ      4     // j-chunks per level in k_rank

// ---------------------------------------------------------------------------
// ws layout (bytes):
//   scA    : BATCH*LEN0 f32   @ 0x000000
//   scB    : BATCH*LEN0 f32   @ 0x040000
//   rank   : BATCH*LEN0 u32   @ 0x080000
//   ior    : BATCH*LEN0 u32   @ 0x0C0000  (idx_of_rank)
//   liA    : BATCH*LEN0 u32   @ 0x100000  (leaf-index lists)
//   lwA    : BATCH*LEN0 f32   @ 0x140000  (leaf-weight lists)
//   liB    : BATCH*LEN0 u32   @ 0x180000
//   lwB    : BATCH*LEN0 f32   @ 0x1C0000
//   rankp  : NJ*BATCH*LEN0 u32 @ 0x200000 (partial counts, 1 MiB)
//   flagdst: BATCH*LEN0 u32   @ 0x300000  (bit31 = top-half flag, low = dst)
// total 3.25 MiB
// ---------------------------------------------------------------------------

// Bit-faithful replication of numpy's SIMD float32 exp — DO NOT TOUCH.
// (Round 5 proved this is the exact variable that makes ranks match the
// numpy golden: Horner + fnmadd reduction + exponent-bit scale.)
__device__ __forceinline__ float npy_expf(float x) {
    const float q = rintf(__fmul_rn(x, 1.44269504088896341f)); // LOG2EF
    float r = __fmaf_rn(q, -0.693359375f, x);       // fnmadd(q, C1, x)
    r = __fmaf_rn(q, 2.12194440e-4f, r);            // fnmadd(q, C2, x), C2 negative
    const float r2 = __fmul_rn(r, r);
    float p = 1.9875691500E-4f;
    p = __fmaf_rn(p, r, 1.3981999507E-3f);
    p = __fmaf_rn(p, r, 8.3334519073E-3f);
    p = __fmaf_rn(p, r, 4.1665795894E-2f);
    p = __fmaf_rn(p, r, 1.6666665459E-1f);
    p = __fmaf_rn(p, r, 5.0000001201E-1f);
    p = __fmaf_rn(p, r2, r);
    p = __fadd_rn(p, 1.0f);
    const int qi = (int)q;
    const float sc = __uint_as_float((uint32_t)((qi + 127) << 23));
    return __fmul_rn(p, sc);
}

// Chunked rank-by-count, stable (ascending-index) tie order. Unchanged from
// round 6 (verified). Rank values bit-identical to monolithic version.
__global__ __launch_bounds__(256) void k_rank(const float* __restrict__ sc,
                                              uint32_t* __restrict__ rankp,
                                              int L, int C) {
    __shared__ float keys[2048];             // C <= 2048 -> 8 KiB
    const int b    = blockIdx.z;
    const int base = b * LEN0;
    const int tid  = threadIdx.x;
    const int ib   = blockIdx.x * 256;
    const int jb   = blockIdx.y * C;

    for (int j = tid; j < C; j += 256)
        keys[j] = sc[base + jb + j];
    __syncthreads();

    const int i = ib + tid;
    const float me = sc[base + i];

    uint32_t cnt = 0;
    if (jb + C <= ib) {
        for (int j = 0; j < C; j += 4) {          // all j < i: ties count
            const float4 kv = *(const float4*)&keys[j];
            cnt += (kv.x >= me);
            cnt += (kv.y >= me);
            cnt += (kv.z >= me);
            cnt += (kv.w >= me);
        }
    } else if (jb >= ib + 256) {
        for (int j = 0; j < C; j += 4) {          // all j > i: ties don't
            const float4 kv = *(const float4*)&keys[j];
            cnt += (kv.x > me);
            cnt += (kv.y > me);
            cnt += (kv.z > me);
            cnt += (kv.w > me);
        }
    } else {
        for (int j = 0; j < C; j += 4) {          // diagonal: full predicate
            const float4 kv = *(const float4*)&keys[j];
            const int jj = jb + j;
            cnt += (kv.x > me) || (kv.x == me && (jj    ) < i);
            cnt += (kv.y > me) || (kv.y == me && (jj + 1) < i);
            cnt += (kv.z > me) || (kv.z == me && (jj + 2) < i);
            cnt += (kv.w > me) || (kv.w == me && (jj + 3) < i);
        }
    }
    rankp[(size_t)blockIdx.y * (BATCH * LEN0) + base + i] = cnt;
}

// Per-batch light pass: sum NJ partials -> rank, scatter ior, flag top-half,
// block-wide prefix scan -> packed flag|dst.  One block (1024 thr) per batch.
__global__ __launch_bounds__(1024) void k_scan(const uint32_t* __restrict__ rankp,
                                               uint32_t* __restrict__ rank,
                                               uint32_t* __restrict__ ior,
                                               uint32_t* __restrict__ flagdst,
                                               int L) {
    __shared__ uint32_t part[1024];
    const int b    = blockIdx.x;
    const int base = b * LEN0;
    const int tid  = threadIdx.x;
    const int R    = L / 1024;           // 8,4,2,1
    const int i0   = tid * R;
    const uint32_t half = (uint32_t)(L / 2);

    uint32_t floc[8], dloc[8];
    uint32_t loc = 0;
    for (int k = 0; k < R; k++) {
        const int i = i0 + k;
        uint32_t r = 0;
        #pragma unroll
        for (int c = 0; c < NJ; c++)
            r += rankp[(size_t)c * (BATCH * LEN0) + base + i];
        rank[base + i] = r;
        ior[base + r] = (uint32_t)i;
        const uint32_t f = (r < half) ? 1u : 0u;
        floc[k] = f;
        dloc[k] = loc;
        loc += f;
    }
    part[tid] = loc;
    __syncthreads();
    for (int off = 1; off < 1024; off <<= 1) {   // Hillis-Steele inclusive
        uint32_t v = part[tid];
        uint32_t add = (tid >= off) ? part[tid - off] : 0u;
        __syncthreads();
        part[tid] = v + add;
        __syncthreads();
    }
    const uint32_t dbase = (tid > 0) ? part[tid - 1] : 0u;
    for (int k = 0; k < R; k++)
        flagdst[base + i0 + k] = (floc[k] << 31) | (dbase + dloc[k]);
}

// Wide per-pair work: softmax (NUMERICS FROZEN, round 5) + leaf-list merge.
// One thread per row i; only top-half rows act.  W==1 writes identity leaves.
__global__ __launch_bounds__(256) void k_pairwork(const float* __restrict__ sc_cur,
                                                  float* __restrict__ sc_nxt,
                                                  const uint32_t* __restrict__ rank,
                                                  const uint32_t* __restrict__ ior,
                                                  const uint32_t* __restrict__ flagdst,
                                                  const uint32_t* __restrict__ li_cur,
                                                  const float* __restrict__ lw_cur,
                                                  uint32_t* __restrict__ li_nxt,
                                                  float* __restrict__ lw_nxt,
                                                  int L, int W) {
    const int b    = blockIdx.y;
    const int base = b * LEN0;
    const int i    = blockIdx.x * 256 + threadIdx.x;

    const uint32_t fd = flagdst[base + i];
    if (!(fd >> 31)) return;
    const uint32_t dst = fd & 0x7FFFFFFFu;

    const uint32_t r = rank[base + i];
    const uint32_t p = ior[base + (uint32_t)(L - 1) - r];

    const float s0 = sc_cur[base + i];
    const float s1 = sc_cur[base + p];
    // np.power(2.0, s): glibc powf (correctly rounded); exp2 in double
    // rounded to f32 reproduces it.
    const float p0 = (float)exp2((double)s0);
    const float p1 = (float)exp2((double)s1);
    const float mx = fmaxf(p0, p1);
    const float d0 = __fsub_rn(p0, mx);
    const float d1 = __fsub_rn(p1, mx);
    const float e0 = npy_expf(d0);
    const float e1 = npy_expf(d1);
    const float den = __fadd_rn(e0, e1);
    const float w0 = __fdiv_rn(e0, den);
    const float w1 = __fdiv_rn(e1, den);
    const float ns = __fadd_rn(__fmul_rn(s0, w0), __fmul_rn(s1, w1));

    sc_nxt[base + dst] = ns;

    uint32_t* lo = li_nxt + base + dst * 2 * W;
    float*    wo = lw_nxt + base + dst * 2 * W;
    if (W == 1) {
        lo[0] = (uint32_t)i; wo[0] = w0;     // level-0 leaves are identity
        lo[1] = p;           wo[1] = w1;
    } else {
        const uint32_t* liA = li_cur + base + i * W;
        const float*    lwA = lw_cur + base + i * W;
        const uint32_t* liB = li_cur + base + p * W;
        const float*    lwB = lw_cur + base + p * W;
        for (int k2 = 0; k2 < W; k2++) { lo[k2]     = liA[k2]; wo[k2]     = __fmul_rn(w0, lwA[k2]); }
        for (int k2 = 0; k2 < W; k2++) { lo[W + k2] = liB[k2]; wo[W + k2] = __fmul_rn(w1, lwB[k2]); }
    }
}

// final gather: out[b,s,:] = sum_{k<16} w_k * emb[b, idx_k, :]
__global__ __launch_bounds__(192) void k_merge(const float* __restrict__ emb,
                                               const uint32_t* __restrict__ li,
                                               const float* __restrict__ lw,
                                               const float* __restrict__ sc_fin,
                                               float* __restrict__ out) {
    __shared__ uint32_t idx[16];
    __shared__ float    w[16];
    const int s = blockIdx.x;
    const int b = blockIdx.y;
    const int d = threadIdx.x;

    if (d < 16) {
        idx[d] = li[b * LEN0 + s * 16 + d];
        w[d]   = lw[b * LEN0 + s * 16 + d];
    }
    __syncthreads();

    const float* ebase = emb + (size_t)b * LEN0 * EMB;
    float4 acc = make_float4(0.f, 0.f, 0.f, 0.f);
    #pragma unroll
    for (int k = 0; k < 16; k++) {
        const float4 v = *(const float4*)(ebase + (size_t)idx[k] * EMB + d * 4);
        const float wk = w[k];
        acc.x += wk * v.x; acc.y += wk * v.y; acc.z += wk * v.z; acc.w += wk * v.w;
    }
    *(float4*)(out + ((size_t)b * POOLED + s) * EMB + d * 4) = acc;
    if (d == 0)
        out[(size_t)BATCH * POOLED * EMB + b * POOLED + s] = sc_fin[b * LEN0 + s];
}

extern "C" void kernel_launch(void* const* d_in, const int* in_sizes, int n_in,
                              void* d_out, int out_size, void* d_ws, size_t ws_size,
                              hipStream_t stream) {
    const float* embs   = (const float*)d_in[0];
    const float* scores = (const float*)d_in[1];
    float* out = (float*)d_out;
    char* ws = (char*)d_ws;

    float*    scA     = (float*)(ws + 0x000000);
    float*    scB     = (float*)(ws + 0x040000);
    uint32_t* rank    = (uint32_t*)(ws + 0x080000);
    uint32_t* ior     = (uint32_t*)(ws + 0x0C0000);
    uint32_t* liA     = (uint32_t*)(ws + 0x100000);
    float*    lwA     = (float*)(ws + 0x140000);
    uint32_t* liB     = (uint32_t*)(ws + 0x180000);
    float*    lwB     = (float*)(ws + 0x1C0000);
    uint32_t* rankp   = (uint32_t*)(ws + 0x200000);
    uint32_t* flagdst = (uint32_t*)(ws + 0x300000);

    // level-0 scores come straight from the input ([B,8192,1] flat layout
    // equals [B*8192]); level-0 leaves are implicit (W==1 identity path).
    const float* sc_cur = scores;
    float*       sc_nxt = scA;
    uint32_t *li_cur = liA, *li_nxt = liB;
    float    *lw_cur = lwA, *lw_nxt = lwB;

    int L = LEN0;
    for (int l = 0; l < NDEPTH; l++) {
        const int W = 1 << l;
        const int C = L / NJ;            // 2048,1024,512,256
        k_rank<<<dim3(L / 256, NJ, BATCH), 256, 0, stream>>>(sc_cur, rankp, L, C);
        k_scan<<<BATCH, 1024, 0, stream>>>(rankp, rank, ior, flagdst, L);
        k_pairwork<<<dim3(L / 256, BATCH), 256, 0, stream>>>(
            sc_cur, sc_nxt, rank, ior, flagdst,
            li_cur, lw_cur, li_nxt, lw_nxt, L, W);
        sc_cur = sc_nxt;
        sc_nxt = (sc_cur == scA) ? scB : scA;
        { uint32_t* t = li_cur; li_cur = li_nxt; li_nxt = t; }
        { float* t = lw_cur; lw_cur = lw_nxt; lw_nxt = t; }
        L >>= 1;
    }

    k_merge<<<dim3(POOLED, BATCH), 192, 0, stream>>>(embs, li_cur, lw_cur,
                                                     (const float*)sc_cur, out);
}